// Round 8
// baseline (2026.777 us; speedup 1.0000x reference)
//
#include <hip/hip_runtime.h>
#include <stdint.h>

#define IN_F   512
#define OUT_F  512
#define BATCH  512
#define NWG    128
#define TPB    256
#define BAND   4   // NWG*BAND == OUT_F

#define SENT 0xFFFFFFFFu

typedef unsigned int uint4v __attribute__((ext_vector_type(4)));

__device__ __forceinline__ float4 ld4(const float* p) {
    return *reinterpret_cast<const float4*>(p);
}
__device__ __forceinline__ float clmp1(float v) {
    return fminf(1.0f, fmaxf(-1.0f, v));
}
__device__ __forceinline__ float wsum(float v) {
#pragma unroll
    for (int o = 32; o > 0; o >>= 1) v += __shfl_xor(v, o);
    return v;
}
__device__ __forceinline__ float wmaxr(float v) {
#pragma unroll
    for (int o = 32; o > 0; o >>= 1) v = fmaxf(v, __shfl_xor(v, o));
    return v;
}

// One shadow row: accumulate the 5 per-column linearization dots + hull maxes.
// Targets (relative to the iteration s that will CONSUME these at s'=s+1):
//   A1,B1: l(s'+1) = A1 + B1*xo(s')      [exact linear form]
//   At,G : A2(s'+2) = At + G*xo(s')      [trace-base folded]
//   B2   : slope of l(s'+2) in xo(s'+1)
__device__ __forceinline__ void shrow(
    const float4& t, const float4& m1, const float4& m2,
    const float4& w4, const float4& a4,
    float x1r, float x2r, float x3r,
    float qA1[4], float qB1[4], float qAt[4], float qG[4], float qB2[4],
    float& hb1, float& hs1, float& hb2, float& h1, float& h2)
{
    const float tt[4] = {t.x, t.y, t.z, t.w};
    const float e1[4] = {m1.x, m1.y, m1.z, m1.w};
    const float e2[4] = {m2.x, m2.y, m2.z, m2.w};
    const float ww[4] = {w4.x, w4.y, w4.z, w4.w};
    const float aa[4] = {a4.x, a4.y, a4.z, a4.w};
    const float ax1 = fabsf(x1r), ax2 = fabsf(x2r);
#pragma unroll
    for (int k = 0; k < 4; ++k) {
        float b1 = (1.f - e1[k]) * tt[k];       // (1-eta_mid)*tr
        float b2 = (1.f - e2[k]) * b1;          // (1-eta_hi)*(1-eta_mid)*tr
        qA1[k] += x2r * (ww[k] + aa[k] * b1);
        qB1[k] += x2r * aa[k] * e1[k] * x1r;
        qAt[k] += x3r * (ww[k] + aa[k] * b2);
        qG[k]  += x3r * aa[k] * (1.f - e2[k]) * e1[k] * x1r;
        qB2[k] += x3r * aa[k] * e2[k] * x2r;
        hb1 = fmaxf(hb1, fabsf(b1));
        hb2 = fmaxf(hb2, fabsf(b2));
        float s1 = e1[k] * ax1;
        hs1 = fmaxf(hs1, s1);
        h1  = fmaxf(h1, (1.f - e2[k]) * s1);
        h2  = fmaxf(h2, e2[k] * ax2);
    }
}

// Exchange protocol (lead-2 pipelined): pairs[t*NWG+j] = (P,Q) bits with
// u_j(t) ~= P + Q/S(t-1); S(t) = sum_j P_j + (sum_j Q_j)/S(t-1).
// Pairs for step t are normally published two iterations early (Taylor,
// rel. err ~1e-7); on hull-guard failure they arrive late but exact (Q=0).
// Sentinel 0xFFFFFFFF per dword is never a published value (P>0 finite,
// Q finite). Payload rides inside the 8B word -> relaxed agent scope.
__global__ __launch_bounds__(TPB, 1) void plastic_scan_kernel(
    const float* __restrict__ x,      // [BATCH][IN_F]
    const float* __restrict__ eta,    // [BATCH][IN_F][OUT_F]
    const float* __restrict__ w,      // [IN_F][OUT_F]
    const float* __restrict__ alpha,  // [IN_F][OUT_F]
    float* __restrict__ out,          // [BATCH][OUT_F]
    unsigned long long* __restrict__ pairs) // [BATCH][NWG], sentinel 0xFF
{
    __shared__ float wred[4][25];  // per-wave shadow partials
    __shared__ float wredL[4][4];  // honest-logit partials (fallback)
    __shared__ float fAB[25];      // folded shadow
    __shared__ __align__(16) float sXO[4];
    __shared__ unsigned int sFlag;

    const int tid = threadIdx.x;
    const int wv  = tid >> 6;
    const int pb  = blockIdx.x;
    const int j    = ((pb & 7) * (NWG / 8)) + (pb >> 3);  // XCD-banded remap
    const int col0 = j * BAND;
    const int r0 = tid;
    const int r1 = tid + TPB;

    const size_t estep = (size_t)IN_F * OUT_F;
    const float* ebase = eta + col0;

    // ---- persistent per-thread state (registers) ----
    float4 wA = ld4(&w[(size_t)r0 * OUT_F + col0]);
    float4 wB = ld4(&w[(size_t)r1 * OUT_F + col0]);
    float4 aA = ld4(&alpha[(size_t)r0 * OUT_F + col0]);
    float4 aB = ld4(&alpha[(size_t)r1 * OUT_F + col0]);
    float4 trA = make_float4(0.f, 0.f, 0.f, 0.f);
    float4 trB = make_float4(0.f, 0.f, 0.f, 0.f);
    const float4 z4 = make_float4(0.f, 0.f, 0.f, 0.f);

    // eta ring: er0=eta(s), er1=eta(s+1), er2=eta(s+2)
    float4 er0A = ld4(ebase + 0 * estep + (size_t)r0 * OUT_F);
    float4 er0B = ld4(ebase + 0 * estep + (size_t)r1 * OUT_F);
    float4 er1A = ld4(ebase + 1 * estep + (size_t)r0 * OUT_F);
    float4 er1B = ld4(ebase + 1 * estep + (size_t)r1 * OUT_F);
    float4 er2A = ld4(ebase + 2 * estep + (size_t)r0 * OUT_F);
    float4 er2B = ld4(ebase + 2 * estep + (size_t)r1 * OUT_F);
    // x ring: xP=x(s), x1..x3 = x(s+1..s+3)
    float xPA = x[r0],            xPB = x[r1];
    float x1A = x[IN_F + r0],     x1B = x[IN_F + r1];
    float x2A = x[2 * IN_F + r0], x2B = x[2 * IN_F + r1];
    float x3A = x[3 * IN_F + r0], x3B = x[3 * IN_F + r1];

    // lane0 persistent: own exp(l) for current step, S recurrence, publish mark
    float e0 = 0, e1 = 0, e2 = 0, e3 = 0;
    float S_prev = 1.0f;
    int pubHi = 0;

    // shadow block (writes wred[wv])
    auto doShadow = [&](const float4& tA, const float4& tB,
                        const float4& m1A, const float4& m1B,
                        const float4& m2A, const float4& m2B,
                        float xa1, float xb1, float xa2, float xb2,
                        float xa3, float xb3) {
        float qA1[4] = {0,0,0,0}, qB1[4] = {0,0,0,0}, qAt[4] = {0,0,0,0};
        float qG[4] = {0,0,0,0}, qB2[4] = {0,0,0,0};
        float hb1 = 0, hs1 = 0, hb2 = 0, h1 = 0, h2 = 0;
        shrow(tA, m1A, m2A, wA, aA, xa1, xa2, xa3, qA1, qB1, qAt, qG, qB2,
              hb1, hs1, hb2, h1, h2);
        shrow(tB, m1B, m2B, wB, aB, xb1, xb2, xb3, qA1, qB1, qAt, qG, qB2,
              hb1, hs1, hb2, h1, h2);
#pragma unroll
        for (int k = 0; k < 4; ++k) {
            qA1[k] = wsum(qA1[k]); qB1[k] = wsum(qB1[k]); qAt[k] = wsum(qAt[k]);
            qG[k] = wsum(qG[k]);   qB2[k] = wsum(qB2[k]);
        }
        hb1 = wmaxr(hb1); hs1 = wmaxr(hs1); hb2 = wmaxr(hb2);
        h1 = wmaxr(h1);   h2 = wmaxr(h2);
        if ((tid & 63) == 0) {
            float* wr = wred[wv];
#pragma unroll
            for (int k = 0; k < 4; ++k) {
                wr[k] = qA1[k]; wr[4 + k] = qB1[k]; wr[8 + k] = qAt[k];
                wr[12 + k] = qG[k]; wr[16 + k] = qB2[k];
            }
            wr[20] = hb1; wr[21] = hs1; wr[22] = hb2; wr[23] = h1; wr[24] = h2;
        }
    };
    // honest l(s+1) dot from current tr(s+1), x1 (writes wredL[wv])
    auto honestDot = [&]() {
        float p0 = x1A * (wA.x + aA.x * trA.x) + x1B * (wB.x + aB.x * trB.x);
        float p1 = x1A * (wA.y + aA.y * trA.y) + x1B * (wB.y + aB.y * trB.y);
        float p2 = x1A * (wA.z + aA.z * trA.z) + x1B * (wB.z + aB.z * trB.z);
        float p3 = x1A * (wA.w + aA.w * trA.w) + x1B * (wB.w + aB.w * trB.w);
        p0 = wsum(p0); p1 = wsum(p1); p2 = wsum(p2); p3 = wsum(p3);
        if ((tid & 63) == 0) {
            wredL[wv][0] = p0; wredL[wv][1] = p1;
            wredL[wv][2] = p2; wredL[wv][3] = p3;
        }
    };
    auto publish = [&](int t, float P, float Q) {
        union { float f[2]; unsigned long long u; } pk;
        pk.f[0] = P; pk.f[1] = Q;
        __hip_atomic_store(&pairs[(size_t)t * NWG + j], pk.u,
                           __ATOMIC_RELAXED, __HIP_MEMORY_SCOPE_AGENT);
    };

    // ================= prologue =================
    {   // honest l(0) = x(0) @ w  (trace(0)=0)
        float p0 = xPA * wA.x + xPB * wB.x;
        float p1 = xPA * wA.y + xPB * wB.y;
        float p2 = xPA * wA.z + xPB * wB.z;
        float p3 = xPA * wA.w + xPB * wB.w;
        p0 = wsum(p0); p1 = wsum(p1); p2 = wsum(p2); p3 = wsum(p3);
        if ((tid & 63) == 0) {
            wredL[wv][0] = p0; wredL[wv][1] = p1;
            wredL[wv][2] = p2; wredL[wv][3] = p3;
        }
    }
    // prologue shadow for iteration 0: tr=0, mid=eta(0), hi=eta(1),
    // x1->x(0), x2->x(1), x3->x(2)
    doShadow(z4, z4, er0A, er0B, er1A, er1B, xPA, xPB, x1A, x1B, x2A, x2B);
    __syncthreads();
    if (tid == 0) {
        float l0 = wredL[0][0] + wredL[1][0] + wredL[2][0] + wredL[3][0];
        float l1 = wredL[0][1] + wredL[1][1] + wredL[2][1] + wredL[3][1];
        float l2 = wredL[0][2] + wredL[1][2] + wredL[2][2] + wredL[3][2];
        float l3 = wredL[0][3] + wredL[1][3] + wredL[2][3] + wredL[3][3];
        e0 = __expf(l0); e1 = __expf(l1); e2 = __expf(l2); e3 = __expf(l3);
        publish(0, (e0 + e1) + (e2 + e3), 0.f);
    }

    // ================= steady loop =================
    for (int s = 0; s < BATCH; ++s) {
        // issue hiding prefetches: eta(s+3), x(s+4)
        float4 er3A = z4, er3B = z4;
        float x4A = 0.f, x4B = 0.f;
        if (s + 3 < BATCH) {
            er3A = ld4(ebase + (size_t)(s + 3) * estep + (size_t)r0 * OUT_F);
            er3B = ld4(ebase + (size_t)(s + 3) * estep + (size_t)r1 * OUT_F);
        }
        if (s + 4 < BATCH) {
            x4A = x[(size_t)(s + 4) * IN_F + r0];
            x4B = x[(size_t)(s + 4) * IN_F + r1];
        }
        // fold previous shadow: lanes 0..24 of wave 0
        if (tid < 25) {
            float a_ = wred[0][tid], b_ = wred[1][tid];
            float c_ = wred[2][tid], d_ = wred[3][tid];
            fAB[tid] = (tid < 20) ? ((a_ + b_) + (c_ + d_))
                                  : fmaxf(fmaxf(a_, b_), fmaxf(c_, d_));
        }
        // lane0: pick up folded coefficients before the poll
        float cA1[4], cB1[4], cAt[4], cG[4], cB2[4], hh[5];
        if (tid == 0) {
#pragma unroll
            for (int k = 0; k < 4; ++k) {
                cA1[k] = fAB[k]; cB1[k] = fAB[4 + k]; cAt[k] = fAB[8 + k];
                cG[k] = fAB[12 + k]; cB2[k] = fAB[16 + k];
            }
#pragma unroll
            for (int k = 0; k < 5; ++k) hh[k] = fAB[20 + k];
        }
        // ---- poll pairs(s): one dwordx4 per lane = 2 pairs ----
        float sumP = 0.f, sumQ = 0.f;
        if (tid < 64) {
            const unsigned long long* pp = pairs + (size_t)s * NWG + 2 * tid;
            uint4v v;
            for (;;) {
                asm volatile("global_load_dwordx4 %0, %1, off sc0 sc1\n\t"
                             "s_waitcnt vmcnt(0)"
                             : "=v"(v) : "v"(pp) : "memory");
                if (__all((v.x != SENT) & (v.y != SENT) &
                          (v.z != SENT) & (v.w != SENT))) break;
            }
            sumP = wsum(__uint_as_float(v.x) + __uint_as_float(v.z));
            sumQ = wsum(__uint_as_float(v.y) + __uint_as_float(v.w));
        }
        // ---- lane0: S recurrence, softmax, pipelined publishes ----
        if (tid == 0) {
            float S = sumP + sumQ / S_prev;
            S_prev = S;
            float rS = 1.0f / S;
            float xo0 = e0 * rS, xo1 = e1 * rS, xo2 = e2 * rS, xo3 = e3 * rS;
            sXO[0] = xo0; sXO[1] = xo1; sXO[2] = xo2; sXO[3] = xo3;
            *(float4*)&out[(size_t)s * OUT_F + col0] =
                make_float4(xo0, xo1, xo2, xo3);
            unsigned int flag = 0u;
            if (s < BATCH - 1) {
                float xom = fmaxf(fmaxf(xo0, xo1), fmaxf(xo2, xo3));
                bool g1 = (hh[0] + hh[1] * xom) <= 1.0f;
                bool g2 = (hh[2] + (hh[3] + 16.f * hh[4]) * xom) <= 1.0f;
                if (g1) {
                    float n0 = __expf(cA1[0] + cB1[0] * xo0);
                    float n1 = __expf(cA1[1] + cB1[1] * xo1);
                    float n2 = __expf(cA1[2] + cB1[2] * xo2);
                    float n3 = __expf(cA1[3] + cB1[3] * xo3);
                    if (pubHi == s) {  // pair(s+1) not yet out: exact publish
                        publish(s + 1, (n0 + n1) + (n2 + n3), 0.f);
                        pubHi = s + 1;
                    }
                    if (g2 && s + 2 <= BATCH - 1 && pubHi == s + 1) {
                        float a0 = __expf(cAt[0] + cG[0] * xo0);
                        float a1 = __expf(cAt[1] + cG[1] * xo1);
                        float a2 = __expf(cAt[2] + cG[2] * xo2);
                        float a3 = __expf(cAt[3] + cG[3] * xo3);
                        float P = (a0 + a1) + (a2 + a3);
                        float Q = ((a0 * cB2[0]) * n0 + (a1 * cB2[1]) * n1) +
                                  ((a2 * cB2[2]) * n2 + (a3 * cB2[3]) * n3);
                        publish(s + 2, P, Q);
                        pubHi = s + 2;
                    }
                    e0 = n0; e1 = n1; e2 = n2; e3 = n3;
                } else {
                    flag = (pubHi == s) ? 1u : 2u;  // honest (publish / no-pub)
                }
            }
            sFlag = flag;
        }
        __syncthreads();
        if (s == BATCH - 1) break;

        const unsigned int flag = sFlag;
        const float xo0 = sXO[0], xo1 = sXO[1], xo2 = sXO[2], xo3 = sXO[3];

        // ---- trace(s+1) = clip((1-eta(s))*tr + eta(s)*x(s)*xo(s)) ----
        trA.x = clmp1((1.f - er0A.x) * trA.x + er0A.x * (xPA * xo0));
        trA.y = clmp1((1.f - er0A.y) * trA.y + er0A.y * (xPA * xo1));
        trA.z = clmp1((1.f - er0A.z) * trA.z + er0A.z * (xPA * xo2));
        trA.w = clmp1((1.f - er0A.w) * trA.w + er0A.w * (xPA * xo3));
        trB.x = clmp1((1.f - er0B.x) * trB.x + er0B.x * (xPB * xo0));
        trB.y = clmp1((1.f - er0B.y) * trB.y + er0B.y * (xPB * xo1));
        trB.z = clmp1((1.f - er0B.z) * trB.z + er0B.z * (xPB * xo2));
        trB.w = clmp1((1.f - er0B.w) * trB.w + er0B.w * (xPB * xo3));

        if (flag) {  // uniform, rare: honest e(s+1) (+ late exact publish)
            honestDot();
            __syncthreads();
            if (tid == 0) {
                float l0 = wredL[0][0] + wredL[1][0] + wredL[2][0] + wredL[3][0];
                float l1 = wredL[0][1] + wredL[1][1] + wredL[2][1] + wredL[3][1];
                float l2 = wredL[0][2] + wredL[1][2] + wredL[2][2] + wredL[3][2];
                float l3 = wredL[0][3] + wredL[1][3] + wredL[2][3] + wredL[3][3];
                e0 = __expf(l0); e1 = __expf(l1);
                e2 = __expf(l2); e3 = __expf(l3);
                if (flag == 1u) {
                    publish(s + 1, (e0 + e1) + (e2 + e3), 0.f);
                    pubHi = s + 1;
                }
            }
        }

        // ---- shadow for next iteration's publishes ----
        if (s + 2 <= BATCH - 1) {
            doShadow(trA, trB, er1A, er1B, er2A, er2B,
                     x1A, x1B, x2A, x2B, x3A, x3B);
        }

        // rotate rings
        er0A = er1A; er0B = er1B; er1A = er2A; er1B = er2B;
        er2A = er3A; er2B = er3B;
        xPA = x1A; xPB = x1B; x1A = x2A; x1B = x2B;
        x2A = x3A; x2B = x3B; x3A = x4A; x3B = x4B;
        __syncthreads();  // wred/sXO stable for next iteration
    }
}

extern "C" void kernel_launch(void* const* d_in, const int* in_sizes, int n_in,
                              void* d_out, int out_size, void* d_ws, size_t ws_size,
                              hipStream_t stream) {
    const float* x     = (const float*)d_in[0];
    const float* eta   = (const float*)d_in[1];
    const float* w     = (const float*)d_in[2];
    // d_in[3] = b: scalar added to all logits -> cancels in softmax, unused
    const float* alpha = (const float*)d_in[4];
    float* out = (float*)d_out;
    unsigned long long* pairs = (unsigned long long*)d_ws;

    // sentinel-init pair slots: 512*128*8B = 512 KiB
    hipMemsetAsync(d_ws, 0xFF,
                   (size_t)BATCH * NWG * sizeof(unsigned long long), stream);

    plastic_scan_kernel<<<dim3(NWG), dim3(TPB), 0, stream>>>(
        x, eta, w, alpha, out, pairs);
}

// Round 9
// 1932.710 us; speedup vs baseline: 1.0487x; 1.0487x over previous
//
#include <hip/hip_runtime.h>
#include <stdint.h>

#define IN_F   512
#define OUT_F  512
#define BATCH  512
#define NWG    128
#define TPB    128   // 2 waves; 4 rows/thread
#define BAND   4     // NWG*BAND == OUT_F
#define ROWS   4     // IN_F / TPB

#define SENT 0xFFFFFFFFu

typedef unsigned int uint2v __attribute__((ext_vector_type(2)));

static __device__ __forceinline__ float4 ld4(const float* p) {
    return *reinterpret_cast<const float4*>(p);
}
static __device__ __forceinline__ float clmp1(float v) {
    return fminf(1.0f, fmaxf(-1.0f, v));
}
static __device__ __forceinline__ float wsum(float v) {
#pragma unroll
    for (int o = 32; o > 0; o >>= 1) v += __shfl_xor(v, o);
    return v;
}
static __device__ __forceinline__ float wmaxr(float v) {
#pragma unroll
    for (int o = 32; o > 0; o >>= 1) v = fmaxf(v, __shfl_xor(v, o));
    return v;
}
static __device__ __forceinline__ float wminr(float v) {
#pragma unroll
    for (int o = 32; o > 0; o >>= 1) v = fminf(v, __shfl_xor(v, o));
    return v;
}

// R3's exchange, restructured for minimal serial latency:
//   msbuf[t*NWG + j] = bits of u_j(t) = sum_{c in band j} exp(l_c(t));
//   max-free softmax is fp32-safe (logits O(0.3)); sentinel never produced;
//   payload rides inside the 4B word -> relaxed agent scope, no fences.
// 2 waves/WG: wave0 lane0 keeps its shadow partials in REGISTERS (no LDS
// round-trip); only wave1's partials cross LDS. Barriers are 2-wave. All
// vmem prefetch is issued post-poll so the poll's vmcnt(0) is clean.
__global__ __launch_bounds__(TPB, 1) void plastic_scan_kernel(
    const float* __restrict__ x,      // [BATCH][IN_F]
    const float* __restrict__ eta,    // [BATCH][IN_F][OUT_F]
    const float* __restrict__ w,      // [IN_F][OUT_F]
    const float* __restrict__ alpha,  // [IN_F][OUT_F]
    float* __restrict__ out,          // [BATCH][OUT_F]
    unsigned int* __restrict__ msbuf) // [BATCH][NWG], sentinel 0xFF
{
    __shared__ float sW1[12];   // wave1 shadow partials: A0..3,B0..3,hbp,hsp,hbn,hsn
    __shared__ float sL[2][4];  // honest-logit partials (prologue / fallback)
    __shared__ __align__(16) float sXO[4];
    __shared__ unsigned int sFlag;

    const int tid = threadIdx.x;
    const int wv  = tid >> 6;
    const int pb  = blockIdx.x;
    const int j    = ((pb & 7) * (NWG / 8)) + (pb >> 3);  // XCD-banded remap
    const int col0 = j * BAND;

    const size_t estep = (size_t)IN_F * OUT_F;
    const float* ebase = eta + col0;

    // ---- per-thread persistent state: 4 rows x 4 cols, all registers ----
    float4 w_[ROWS], a_[ROWS], tr_[ROWS], e0_[ROWS], e1_[ROWS], e2_[ROWS];
    float xP_[ROWS], x1_[ROWS], x2_[ROWS];
#pragma unroll
    for (int k = 0; k < ROWS; ++k) {
        const int r = tid + TPB * k;
        w_[k]  = ld4(&w[(size_t)r * OUT_F + col0]);
        a_[k]  = ld4(&alpha[(size_t)r * OUT_F + col0]);
        tr_[k] = make_float4(0.f, 0.f, 0.f, 0.f);
        e0_[k] = ld4(ebase + (size_t)r * OUT_F);
        e1_[k] = ld4(ebase + estep + (size_t)r * OUT_F);
        e2_[k] = ld4(ebase + 2 * estep + (size_t)r * OUT_F);
        xP_[k] = x[r];
        x1_[k] = x[IN_F + r];
        x2_[k] = x[2 * IN_F + r];
    }

    // wave0's shadow partials (post-reduce, live in every wave0 lane's regs)
    float oA0, oA1, oA2, oA3, oB0, oB1, oB2, oB3, oHbp, oHsp, oHbn, oHsn;
    // lane0 softmax-numerator state
    float es0 = 0, es1 = 0, es2 = 0, es3 = 0;

    // ================= prologue =================
    {
        // honest l(0) = x(0) @ w  (trace(0)=0)
        float p0 = 0, p1 = 0, p2 = 0, p3 = 0;
#pragma unroll
        for (int k = 0; k < ROWS; ++k) {
            p0 += xP_[k] * w_[k].x; p1 += xP_[k] * w_[k].y;
            p2 += xP_[k] * w_[k].z; p3 += xP_[k] * w_[k].w;
        }
        p0 = wsum(p0); p1 = wsum(p1); p2 = wsum(p2); p3 = wsum(p3);
        if ((tid & 63) == 0) {
            sL[wv][0] = p0; sL[wv][1] = p1; sL[wv][2] = p2; sL[wv][3] = p3;
        }
        // shadow for publish target t=1: base=0, slope=eta(0)*x(0)
        float A0 = 0, A1 = 0, A2 = 0, A3 = 0, B0 = 0, B1 = 0, B2 = 0, B3 = 0;
        float hsp = 0.f, hsn = 0.f;
#pragma unroll
        for (int k = 0; k < ROWS; ++k) {
            float4 e = e0_[k], w4 = w_[k], a4 = a_[k];
            float xp = xP_[k], xd = x1_[k];
            float s0 = e.x * xp, s1 = e.y * xp, s2 = e.z * xp, s3 = e.w * xp;
            A0 += xd * w4.x; A1 += xd * w4.y; A2 += xd * w4.z; A3 += xd * w4.w;
            B0 += xd * (a4.x * s0); B1 += xd * (a4.y * s1);
            B2 += xd * (a4.z * s2); B3 += xd * (a4.w * s3);
            hsp = fmaxf(hsp, fmaxf(fmaxf(s0, s1), fmaxf(s2, s3)));
            hsn = fminf(hsn, fminf(fminf(s0, s1), fminf(s2, s3)));
        }
        A0 = wsum(A0); A1 = wsum(A1); A2 = wsum(A2); A3 = wsum(A3);
        B0 = wsum(B0); B1 = wsum(B1); B2 = wsum(B2); B3 = wsum(B3);
        hsp = wmaxr(hsp); hsn = wminr(hsn);
        if (wv == 1 && (tid & 63) == 0) {
            sW1[0] = A0; sW1[1] = A1; sW1[2] = A2; sW1[3] = A3;
            sW1[4] = B0; sW1[5] = B1; sW1[6] = B2; sW1[7] = B3;
            sW1[8] = 0.f; sW1[9] = hsp; sW1[10] = 0.f; sW1[11] = hsn;
        }
        oA0 = A0; oA1 = A1; oA2 = A2; oA3 = A3;
        oB0 = B0; oB1 = B1; oB2 = B2; oB3 = B3;
        oHbp = 0.f; oHsp = hsp; oHbn = 0.f; oHsn = hsn;
    }
    __syncthreads();
    if (tid == 0) {
        float l0 = sL[0][0] + sL[1][0], l1 = sL[0][1] + sL[1][1];
        float l2 = sL[0][2] + sL[1][2], l3 = sL[0][3] + sL[1][3];
        es0 = __expf(l0); es1 = __expf(l1); es2 = __expf(l2); es3 = __expf(l3);
        float u = (es0 + es1) + (es2 + es3);
        __hip_atomic_store(&msbuf[j], __float_as_uint(u),
                           __ATOMIC_RELAXED, __HIP_MEMORY_SCOPE_AGENT);
    }

    // ================= steady loop =================
    for (int t = 0; t < BATCH; ++t) {
        float S = 0.f;
        float A0, A1, A2, A3, B0, B1, B2, B3, Hbp, Hsp, Hbn, Hsn;
        if (tid < 64) {
            if (tid == 0) {  // fold: 12 LDS reads + combine with own regs
                A0 = oA0 + sW1[0]; A1 = oA1 + sW1[1];
                A2 = oA2 + sW1[2]; A3 = oA3 + sW1[3];
                B0 = oB0 + sW1[4]; B1 = oB1 + sW1[5];
                B2 = oB2 + sW1[6]; B3 = oB3 + sW1[7];
                Hbp = fmaxf(oHbp, sW1[8]);  Hsp = fmaxf(oHsp, sW1[9]);
                Hbn = fminf(oHbn, sW1[10]); Hsn = fminf(oHsn, sW1[11]);
            }
            // poll: wave0 has ZERO other outstanding vmem here
            const unsigned int* pa = msbuf + (size_t)t * NWG + 2 * tid;
            uint2v v;
            for (;;) {
                asm volatile("global_load_dwordx2 %0, %1, off sc0 sc1\n\t"
                             "s_waitcnt vmcnt(0)"
                             : "=v"(v) : "v"(pa) : "memory");
                if (__all((v.x != SENT) & (v.y != SENT))) break;
            }
            S = wsum(__uint_as_float(v.x) + __uint_as_float(v.y));
        }
        if (tid == 0) {
            float rS = 1.0f / S;
            float xo0 = es0 * rS, xo1 = es1 * rS, xo2 = es2 * rS, xo3 = es3 * rS;
            unsigned int flag = 1u;
            if (t < BATCH - 1) {
                float xom = fmaxf(fmaxf(xo0, xo1), fmaxf(xo2, xo3));
                bool ok = (Hbp + Hsp * xom <= 1.0f) && (Hbn + Hsn * xom >= -1.0f);
                if (ok) {
                    es0 = __expf(A0 + B0 * xo0); es1 = __expf(A1 + B1 * xo1);
                    es2 = __expf(A2 + B2 * xo2); es3 = __expf(A3 + B3 * xo3);
                    float u = (es0 + es1) + (es2 + es3);
                    __hip_atomic_store(&msbuf[(size_t)(t + 1) * NWG + j],
                                       __float_as_uint(u),
                                       __ATOMIC_RELAXED, __HIP_MEMORY_SCOPE_AGENT);
                } else {
                    flag = 0u;  // defer: honest publish after real trace update
                }
            }
            sXO[0] = xo0; sXO[1] = xo1; sXO[2] = xo2; sXO[3] = xo3;
            sFlag = flag;
        }
        __syncthreads();  // B1
        if (tid == 64) {  // out store on wave1 (never in a vmcnt(0) window)
            *(float4*)&out[(size_t)t * OUT_F + col0] = *(const float4*)&sXO[0];
        }
        if (t == BATCH - 1) break;

        const unsigned int flag = sFlag;
        const float xo0 = sXO[0], xo1 = sXO[1], xo2 = sXO[2], xo3 = sXO[3];

        // issue prefetches now (post-poll): eta(t+3), x(t+3)
        float4 e3_[ROWS];
        float x3_[ROWS];
        if (t + 3 < BATCH) {
#pragma unroll
            for (int k = 0; k < ROWS; ++k) {
                const int r = tid + TPB * k;
                e3_[k] = ld4(ebase + (size_t)(t + 3) * estep + (size_t)r * OUT_F);
                x3_[k] = x[(size_t)(t + 3) * IN_F + r];
            }
        } else {
#pragma unroll
            for (int k = 0; k < ROWS; ++k) {
                e3_[k] = make_float4(0.f, 0.f, 0.f, 0.f);
                x3_[k] = 0.f;
            }
        }

        // trace(t+1) = clip((1-eta(t))*tr + eta(t)*x(t)*xo(t))
#pragma unroll
        for (int k = 0; k < ROWS; ++k) {
            float4 e = e0_[k]; float xp = xP_[k]; float4 tv = tr_[k];
            tv.x = clmp1((1.f - e.x) * tv.x + e.x * (xp * xo0));
            tv.y = clmp1((1.f - e.y) * tv.y + e.y * (xp * xo1));
            tv.z = clmp1((1.f - e.z) * tv.z + e.z * (xp * xo2));
            tv.w = clmp1((1.f - e.w) * tv.w + e.w * (xp * xo3));
            tr_[k] = tv;
        }

        if (!flag) {  // uniform branch, rare: honest l(t+1) from clipped trace
            float p0 = 0, p1 = 0, p2 = 0, p3 = 0;
#pragma unroll
            for (int k = 0; k < ROWS; ++k) {
                float xd = x1_[k];
                p0 += xd * (w_[k].x + a_[k].x * tr_[k].x);
                p1 += xd * (w_[k].y + a_[k].y * tr_[k].y);
                p2 += xd * (w_[k].z + a_[k].z * tr_[k].z);
                p3 += xd * (w_[k].w + a_[k].w * tr_[k].w);
            }
            p0 = wsum(p0); p1 = wsum(p1); p2 = wsum(p2); p3 = wsum(p3);
            if ((tid & 63) == 0) {
                sL[wv][0] = p0; sL[wv][1] = p1; sL[wv][2] = p2; sL[wv][3] = p3;
            }
            __syncthreads();
            if (tid == 0) {
                float l0 = sL[0][0] + sL[1][0], l1 = sL[0][1] + sL[1][1];
                float l2 = sL[0][2] + sL[1][2], l3 = sL[0][3] + sL[1][3];
                es0 = __expf(l0); es1 = __expf(l1);
                es2 = __expf(l2); es3 = __expf(l3);
                float u = (es0 + es1) + (es2 + es3);
                __hip_atomic_store(&msbuf[(size_t)(t + 1) * NWG + j],
                                   __float_as_uint(u),
                                   __ATOMIC_RELAXED, __HIP_MEMORY_SCOPE_AGENT);
            }
        }

        // shadow for publish target t+2: base=(1-eta(t+1))*tr(t+1),
        // slope=eta(t+1)*x(t+1), dot with x(t+2)
        if (t <= BATCH - 3) {
            float sA0 = 0, sA1 = 0, sA2 = 0, sA3 = 0;
            float sB0 = 0, sB1 = 0, sB2 = 0, sB3 = 0;
            float hbp = -1e30f, hbn = 1e30f, hsp = 0.f, hsn = 0.f;
#pragma unroll
            for (int k = 0; k < ROWS; ++k) {
                float4 e = e1_[k], tv = tr_[k], w4 = w_[k], a4 = a_[k];
                float xm = x1_[k], xd = x2_[k];
                float b0 = (1.f - e.x) * tv.x, b1 = (1.f - e.y) * tv.y;
                float b2 = (1.f - e.z) * tv.z, b3 = (1.f - e.w) * tv.w;
                float s0 = e.x * xm, s1 = e.y * xm, s2 = e.z * xm, s3 = e.w * xm;
                sA0 += xd * (w4.x + a4.x * b0); sA1 += xd * (w4.y + a4.y * b1);
                sA2 += xd * (w4.z + a4.z * b2); sA3 += xd * (w4.w + a4.w * b3);
                sB0 += xd * (a4.x * s0); sB1 += xd * (a4.y * s1);
                sB2 += xd * (a4.z * s2); sB3 += xd * (a4.w * s3);
                hbp = fmaxf(hbp, fmaxf(fmaxf(b0, b1), fmaxf(b2, b3)));
                hbn = fminf(hbn, fminf(fminf(b0, b1), fminf(b2, b3)));
                hsp = fmaxf(hsp, fmaxf(fmaxf(s0, s1), fmaxf(s2, s3)));
                hsn = fminf(hsn, fminf(fminf(s0, s1), fminf(s2, s3)));
            }
            sA0 = wsum(sA0); sA1 = wsum(sA1); sA2 = wsum(sA2); sA3 = wsum(sA3);
            sB0 = wsum(sB0); sB1 = wsum(sB1); sB2 = wsum(sB2); sB3 = wsum(sB3);
            hbp = wmaxr(hbp); hsp = wmaxr(hsp);
            hbn = wminr(hbn); hsn = wminr(hsn);
            if (wv == 1 && (tid & 63) == 0) {
                sW1[0] = sA0; sW1[1] = sA1; sW1[2] = sA2; sW1[3] = sA3;
                sW1[4] = sB0; sW1[5] = sB1; sW1[6] = sB2; sW1[7] = sB3;
                sW1[8] = hbp; sW1[9] = hsp; sW1[10] = hbn; sW1[11] = hsn;
            }
            oA0 = sA0; oA1 = sA1; oA2 = sA2; oA3 = sA3;
            oB0 = sB0; oB1 = sB1; oB2 = sB2; oB3 = sB3;
            oHbp = hbp; oHsp = hsp; oHbn = hbn; oHsn = hsn;
        }

        // rotate rings
#pragma unroll
        for (int k = 0; k < ROWS; ++k) {
            e0_[k] = e1_[k]; e1_[k] = e2_[k]; e2_[k] = e3_[k];
            xP_[k] = x1_[k]; x1_[k] = x2_[k]; x2_[k] = x3_[k];
        }
        __syncthreads();  // B2: sW1/sL stable for next iteration
    }
}

extern "C" void kernel_launch(void* const* d_in, const int* in_sizes, int n_in,
                              void* d_out, int out_size, void* d_ws, size_t ws_size,
                              hipStream_t stream) {
    const float* x     = (const float*)d_in[0];
    const float* eta   = (const float*)d_in[1];
    const float* w     = (const float*)d_in[2];
    // d_in[3] = b: scalar added to all logits -> cancels in softmax, unused
    const float* alpha = (const float*)d_in[4];
    float* out = (float*)d_out;
    unsigned int* msbuf = (unsigned int*)d_ws;

    // sentinel-init the per-step exchange slots: 512*128*4B = 256 KiB
    hipMemsetAsync(d_ws, 0xFF, (size_t)BATCH * NWG * sizeof(unsigned int), stream);

    plastic_scan_kernel<<<dim3(NWG), dim3(TPB), 0, stream>>>(
        x, eta, w, alpha, out, msbuf);
}

// Round 11
// 1577.219 us; speedup vs baseline: 1.2850x; 1.2254x over previous
//
#include <hip/hip_runtime.h>
#include <stdint.h>

#define IN_F   512
#define OUT_F  512
#define BATCH  512
#define NWG    128
#define TPB    256
#define BAND   4
#define NR     256          // rounds = BATCH/2
#define SENT   0xFFFFFFFFu

typedef unsigned int uint4v __attribute__((ext_vector_type(4)));
typedef unsigned int uint2v __attribute__((ext_vector_type(2)));

static __device__ __forceinline__ float4 ld4(const float* p) {
    return *reinterpret_cast<const float4*>(p);
}
static __device__ __forceinline__ float clmp1(float v) {
    return fminf(1.f, fmaxf(-1.f, v));
}
static __device__ __forceinline__ float wsum64(float v) {
#pragma unroll
    for (int o = 32; o > 0; o >>= 1) v += __shfl_xor(v, o);
    return v;
}
static __device__ __forceinline__ float wmax64(float v) {
#pragma unroll
    for (int o = 32; o > 0; o >>= 1) v = fmaxf(v, __shfl_xor(v, o));
    return v;
}
static __device__ __forceinline__ float sum4(float v) {
    v += __shfl_xor(v, 1); v += __shfl_xor(v, 2); return v;
}
static __device__ __forceinline__ float max4(float v) {
    v = fmaxf(v, __shfl_xor(v, 1)); v = fmaxf(v, __shfl_xor(v, 2)); return v;
}

// Exchange: slot r (16B/WG) = (u(2r), pad, P(2r+1), Q(2r+1)); one poll per
// 2 steps. S(2r)=Σu; S(2r+1)=ΣP+ΣQ/S(2r) (Taylor, validated R8). All words
// carry payload internally -> relaxed agent scope, no fences. Sentinel
// 0xFFFFFFFF never equals a published word (u,P>0 finite; Q finite; defer
// publishes exact P=u(t),Q=0). Max-free softmax fp32-safe (logits O(0.3)).
__global__ __launch_bounds__(TPB, 1) void plastic_scan_kernel(
    const float* __restrict__ x, const float* __restrict__ eta,
    const float* __restrict__ w, const float* __restrict__ alpha,
    float* __restrict__ out, unsigned int* __restrict__ slots)
{
    __shared__ float wred[4][37];   // shadow partials: 28 coeffs + 9 hulls
    __shared__ float wredL[4][8];   // honest-dot partials
    __shared__ float fAB[37];
    __shared__ __align__(16) float sXO[8];
    __shared__ unsigned sFlags;     // bit0 = honest(gEx fail), bit1 = defer PQ

    const int tid = threadIdx.x;
    const int wv  = tid >> 6;
    const int pb  = blockIdx.x;
    const int j    = ((pb & 7) * (NWG / 8)) + (pb >> 3);
    const int col0 = j * BAND;
    const int r0 = tid, r1 = tid + TPB;

    const size_t estep = (size_t)IN_F * OUT_F;
    const float* eb = eta + col0;

    float4 wA = ld4(&w[(size_t)r0 * OUT_F + col0]);
    float4 wB = ld4(&w[(size_t)r1 * OUT_F + col0]);
    float4 aA = ld4(&alpha[(size_t)r0 * OUT_F + col0]);
    float4 aB = ld4(&alpha[(size_t)r1 * OUT_F + col0]);
    float4 trA = make_float4(0, 0, 0, 0), trB = make_float4(0, 0, 0, 0);
    const float4 z4 = make_float4(0, 0, 0, 0);

    // rings at phase sb=-2: e[k]=eta(sb+k) (k>=2 valid), x[k]=x(sb+k)
    float4 eA0 = z4, eA1 = z4, eB0 = z4, eB1 = z4;
    float4 eA2 = ld4(eb + 0 * estep + (size_t)r0 * OUT_F);
    float4 eB2 = ld4(eb + 0 * estep + (size_t)r1 * OUT_F);
    float4 eA3 = ld4(eb + 1 * estep + (size_t)r0 * OUT_F);
    float4 eB3 = ld4(eb + 1 * estep + (size_t)r1 * OUT_F);
    float4 eA4 = ld4(eb + 2 * estep + (size_t)r0 * OUT_F);
    float4 eB4 = ld4(eb + 2 * estep + (size_t)r1 * OUT_F);
    float xA0 = 0, xA1 = 0, xA2 = x[r0], xA3 = x[IN_F + r0],
          xA4 = x[2 * IN_F + r0], xA5 = x[3 * IN_F + r0];
    float xB0 = 0, xB1 = 0, xB2 = x[r1], xB3 = x[IN_F + r1],
          xB4 = x[2 * IN_F + r1], xB5 = x[3 * IN_F + r1];

    float e_cur = 0, prevLF = 0, prevI = 0;   // lanes 0-3: own column state

    // ---- shadow: coeffs for l(sb+4), l(sb+5) + hulls t=sb+3,4,5 ----
    auto doShadow = [&]() {
        float C[4] = {0,0,0,0}, D[4] = {0,0,0,0}, E[4] = {0,0,0,0};
        float F[4] = {0,0,0,0}, G[4] = {0,0,0,0}, H[4] = {0,0,0,0}, I[4] = {0,0,0,0};
        float h[9] = {0,0,0,0,0,0,0,0,0};
#pragma unroll
        for (int rr = 0; rr < 2; ++rr) {
            const float4 T  = rr ? trB : trA;
            const float4 e2 = rr ? eB2 : eA2, e3 = rr ? eB3 : eA3, e4 = rr ? eB4 : eA4;
            const float x2 = rr ? xB2 : xA2, x3 = rr ? xB3 : xA3;
            const float x4 = rr ? xB4 : xA4, x5 = rr ? xB5 : xA5;
            const float4 w4 = rr ? wB : wA, a4 = rr ? aB : aA;
            const float Tc[4] = {T.x, T.y, T.z, T.w};
            const float e2c[4] = {e2.x, e2.y, e2.z, e2.w};
            const float e3c[4] = {e3.x, e3.y, e3.z, e3.w};
            const float e4c[4] = {e4.x, e4.y, e4.z, e4.w};
            const float wc[4] = {w4.x, w4.y, w4.z, w4.w};
            const float ac[4] = {a4.x, a4.y, a4.z, a4.w};
#pragma unroll
            for (int c = 0; c < 4; ++c) {
                float m2 = 1.f - e2c[c], m3 = 1.f - e3c[c], m4 = 1.f - e4c[c];
                float b3 = m2 * Tc[c],  s3 = e2c[c] * x2;
                float b4 = m3 * b3, s4a = m3 * s3, s4b = e3c[c] * x3;
                float b5 = m4 * b4, s5a = m4 * s4a, s5b = m4 * s4b, s5c = e4c[c] * x4;
                C[c] += x4 * (wc[c] + ac[c] * b4);
                D[c] += x4 * (ac[c] * s4a);
                E[c] += x4 * (ac[c] * s4b);
                F[c] += x5 * (wc[c] + ac[c] * b5);
                G[c] += x5 * (ac[c] * s5a);
                H[c] += x5 * (ac[c] * s5b);
                I[c] += x5 * (ac[c] * s5c);
                h[0] = fmaxf(h[0], fabsf(b3)); h[1] = fmaxf(h[1], fabsf(s3));
                h[2] = fmaxf(h[2], fabsf(b4)); h[3] = fmaxf(h[3], fabsf(s4a));
                h[4] = fmaxf(h[4], fabsf(s4b));
                h[5] = fmaxf(h[5], fabsf(b5)); h[6] = fmaxf(h[6], fabsf(s5a));
                h[7] = fmaxf(h[7], fabsf(s5b)); h[8] = fmaxf(h[8], fabsf(s5c));
            }
        }
#pragma unroll
        for (int c = 0; c < 4; ++c) {
            C[c] = wsum64(C[c]); D[c] = wsum64(D[c]); E[c] = wsum64(E[c]);
            F[c] = wsum64(F[c]); G[c] = wsum64(G[c]); H[c] = wsum64(H[c]);
            I[c] = wsum64(I[c]);
        }
#pragma unroll
        for (int k = 0; k < 9; ++k) h[k] = wmax64(h[k]);
        if ((tid & 63) == 0) {
            float* wr = wred[wv];
#pragma unroll
            for (int c = 0; c < 4; ++c) {
                wr[c] = C[c]; wr[4 + c] = D[c]; wr[8 + c] = E[c];
                wr[12 + c] = F[c]; wr[16 + c] = G[c]; wr[20 + c] = H[c];
                wr[24 + c] = I[c];
            }
#pragma unroll
            for (int k = 0; k < 9; ++k) wr[28 + k] = h[k];
        }
    };
    // honest dot: p_c = Σ rows xw·(w + a·tr) -> wredL[wv][0..3]
    auto dotTr = [&](float xwA, float xwB) {
        float p0 = xwA * (wA.x + aA.x * trA.x) + xwB * (wB.x + aB.x * trB.x);
        float p1 = xwA * (wA.y + aA.y * trA.y) + xwB * (wB.y + aB.y * trB.y);
        float p2 = xwA * (wA.z + aA.z * trA.z) + xwB * (wB.z + aB.z * trB.z);
        float p3 = xwA * (wA.w + aA.w * trA.w) + xwB * (wB.w + aB.w * trB.w);
        p0 = wsum64(p0); p1 = wsum64(p1); p2 = wsum64(p2); p3 = wsum64(p3);
        if ((tid & 63) == 0) {
            wredL[wv][0] = p0; wredL[wv][1] = p1;
            wredL[wv][2] = p2; wredL[wv][3] = p3;
        }
    };

    // ================= prologue =================
    {   // honest l(0): x(0)=xring[2], trace 0
        float p0 = xA2 * wA.x + xB2 * wB.x, p1 = xA2 * wA.y + xB2 * wB.y;
        float p2 = xA2 * wA.z + xB2 * wB.z, p3 = xA2 * wA.w + xB2 * wB.w;
        p0 = wsum64(p0); p1 = wsum64(p1); p2 = wsum64(p2); p3 = wsum64(p3);
        if ((tid & 63) == 0) {
            wredL[wv][0] = p0; wredL[wv][1] = p1;
            wredL[wv][2] = p2; wredL[wv][3] = p3;
        }
    }
    doShadow();                       // phase -2: targets l(2), l(3)
    if (tid == 0) sFlags = 2u;        // round 0 = defer (prologue has no P,Q)
    __syncthreads();
    if (tid < 4) {
        float l = wredL[0][tid] + wredL[1][tid] + wredL[2][tid] + wredL[3][tid];
        e_cur = __expf(l);
        float u = sum4(e_cur);
        if (tid == 0)
            __hip_atomic_store(&slots[(size_t)j * 4], __float_as_uint(u),
                               __ATOMIC_RELAXED, __HIP_MEMORY_SCOPE_AGENT);
    }
    // rotate to phase 0: load eta(3),(4), x(4),(5)
    eA0 = eA2; eA1 = eA3; eA2 = eA4; eB0 = eB2; eB1 = eB3; eB2 = eB4;
    eA3 = ld4(eb + 3 * estep + (size_t)r0 * OUT_F);
    eB3 = ld4(eb + 3 * estep + (size_t)r1 * OUT_F);
    eA4 = ld4(eb + 4 * estep + (size_t)r0 * OUT_F);
    eB4 = ld4(eb + 4 * estep + (size_t)r1 * OUT_F);
    xA0 = xA2; xA1 = xA3; xA2 = xA4; xA3 = xA5;
    xB0 = xB2; xB1 = xB3; xB2 = xB4; xB3 = xB5;
    xA4 = x[4 * IN_F + r0]; xA5 = x[5 * IN_F + r0];
    xB4 = x[4 * IN_F + r1]; xB5 = x[5 * IN_F + r1];
    __syncthreads();  // B2: wred/sFlags ready

    // ================= rounds =================
    for (int r = 0; r < NR; ++r) {
        const int sb = 2 * r;
        const bool deferNow = (sFlags & 2u) != 0u;
        bool trDone1 = false;
        // fold shadow
        if (tid < 37) {
            float a_ = wred[0][tid], b_ = wred[1][tid];
            float c_ = wred[2][tid], d_ = wred[3][tid];
            fAB[tid] = (tid < 28) ? ((a_ + b_) + (c_ + d_))
                                  : fmaxf(fmaxf(a_, b_), fmaxf(c_, d_));
        }
        __syncthreads();  // B3
        float C = 0, D = 0, E = 0, F = 0, G = 0, H = 0, I3 = 0;
        float h0, h1, h2, h3, h4, h5, h6, h7, h8;
        if (tid < 4) {
            C = fAB[tid]; D = fAB[4 + tid]; E = fAB[8 + tid];
            F = fAB[12 + tid]; G = fAB[16 + tid]; H = fAB[20 + tid];
            I3 = fAB[24 + tid];
        }
        if (tid == 0) {
            h0 = fAB[28]; h1 = fAB[29]; h2 = fAB[30]; h3 = fAB[31]; h4 = fAB[32];
            h5 = fAB[33]; h6 = fAB[34]; h7 = fAB[35]; h8 = fAB[36];
        }
        // ---- poll slot r ----
        float S0 = 0, SP = 0, SQ = 0;
        const unsigned* pa = slots + ((size_t)r * NWG + 2 * (tid & 63)) * 4;
        const unsigned* pbb = pa + 4;
        uint4v va, vb;
        if (tid < 64) {
            if (deferNow) {  // phase1: u-words only
                for (;;) {
                    asm volatile("global_load_dwordx4 %0, %2, off sc0 sc1\n\t"
                                 "global_load_dwordx4 %1, %3, off sc0 sc1\n\t"
                                 "s_waitcnt vmcnt(0)"
                                 : "=&v"(va), "=&v"(vb) : "v"(pa), "v"(pbb) : "memory");
                    if (__all((va.x != SENT) & (vb.x != SENT))) break;
                }
                S0 = wsum64(__uint_as_float(va.x) + __uint_as_float(vb.x));
            } else {
                for (;;) {
                    asm volatile("global_load_dwordx4 %0, %2, off sc0 sc1\n\t"
                                 "global_load_dwordx4 %1, %3, off sc0 sc1\n\t"
                                 "s_waitcnt vmcnt(0)"
                                 : "=&v"(va), "=&v"(vb) : "v"(pa), "v"(pbb) : "memory");
                    if (__all((va.x != SENT) & (vb.x != SENT) &
                              (va.z != SENT) & (vb.z != SENT) &
                              (va.w != SENT) & (vb.w != SENT))) break;
                }
                S0 = wsum64(__uint_as_float(va.x) + __uint_as_float(vb.x));
                SP = wsum64(__uint_as_float(va.z) + __uint_as_float(vb.z));
                SQ = wsum64(__uint_as_float(va.w) + __uint_as_float(vb.w));
            }
        }
        float xo0 = 0, xo1 = 0, e1 = 0;
        if (tid < 4) { xo0 = e_cur / S0; sXO[tid] = xo0; }
        if (deferNow) {
            __syncthreads();  // D1: sXO[0..3] ready
            // trace t0->t1 (honest), honest dot l(t1)
            {
                const float4 q = *(const float4*)&sXO[0];
                trA.x = clmp1((1.f - eA0.x) * trA.x + eA0.x * (xA0 * q.x));
                trA.y = clmp1((1.f - eA0.y) * trA.y + eA0.y * (xA0 * q.y));
                trA.z = clmp1((1.f - eA0.z) * trA.z + eA0.z * (xA0 * q.z));
                trA.w = clmp1((1.f - eA0.w) * trA.w + eA0.w * (xA0 * q.w));
                trB.x = clmp1((1.f - eB0.x) * trB.x + eB0.x * (xB0 * q.x));
                trB.y = clmp1((1.f - eB0.y) * trB.y + eB0.y * (xB0 * q.y));
                trB.z = clmp1((1.f - eB0.z) * trB.z + eB0.z * (xB0 * q.z));
                trB.w = clmp1((1.f - eB0.w) * trB.w + eB0.w * (xB0 * q.w));
                trDone1 = true;
            }
            dotTr(xA1, xB1);
            __syncthreads();  // D2
            if (tid < 4) {
                float l = wredL[0][tid] + wredL[1][tid] + wredL[2][tid] + wredL[3][tid];
                e1 = __expf(l);
                float P = sum4(e1);
                if (tid == 0) {
                    uint2v v2; v2.x = __float_as_uint(P); v2.y = 0u;
                    unsigned* pp = slots + ((size_t)r * NWG + j) * 4 + 2;
                    asm volatile("global_store_dwordx2 %0, %1, off sc0 sc1"
                                 :: "v"(pp), "v"(v2) : "memory");
                }
            }
            if (tid < 64) {  // phase2: P,Q words
                for (;;) {
                    asm volatile("global_load_dwordx4 %0, %2, off sc0 sc1\n\t"
                                 "global_load_dwordx4 %1, %3, off sc0 sc1\n\t"
                                 "s_waitcnt vmcnt(0)"
                                 : "=&v"(va), "=&v"(vb) : "v"(pa), "v"(pbb) : "memory");
                    if (__all((va.z != SENT) & (vb.z != SENT) &
                              (va.w != SENT) & (vb.w != SENT))) break;
                }
                SP = wsum64(__uint_as_float(va.z) + __uint_as_float(vb.z));
                SQ = wsum64(__uint_as_float(va.w) + __uint_as_float(vb.w));
            }
        }
        unsigned flbc = 0;
        if (tid < 4) {
            float S1 = SP + SQ / S0;
            if (!deferNow) e1 = __expf(prevLF + prevI * xo0);
            xo1 = e1 / S1; sXO[4 + tid] = xo1;
            float eC  = __expf(C + D * xo0 + E * xo1);
            float lFn = F + G * xo0 + H * xo1;
            float eF  = __expf(lFn);
            float u2 = sum4(eC), P = sum4(eF), Q = sum4(eF * I3 * eC);
            float xom0 = max4(xo0), xom1 = max4(xo1);
            unsigned fl = 0;
            if (tid == 0) {
                if (r <= NR - 2) {
                    bool gEx = (h0 + h1 * xom0 <= 1.f) &&
                               (h2 + h3 * xom0 + h4 * xom1 <= 1.f);
                    float xo2b = fminf(1.f, 32.f * fmaxf(xom0, xom1));
                    bool gH = (h5 + h6 * xom0 + h7 * xom1 + h8 * xo2b <= 1.f);
                    unsigned* sp = slots + ((size_t)(r + 1) * NWG + j) * 4;
                    if (gEx) {
                        if (gH) {
                            uint4v v; v.x = __float_as_uint(u2); v.y = 0u;
                            v.z = __float_as_uint(P); v.w = __float_as_uint(Q);
                            asm volatile("global_store_dwordx4 %0, %1, off sc0 sc1"
                                         :: "v"(sp), "v"(v) : "memory");
                        } else {
                            __hip_atomic_store(sp, __float_as_uint(u2),
                                               __ATOMIC_RELAXED, __HIP_MEMORY_SCOPE_AGENT);
                            fl = 2u;
                        }
                    } else fl = 1u;
                }
                sFlags = fl;
            }
            flbc = __shfl(fl, 0);
            if (!(flbc & 1u)) { e_cur = eC; prevLF = lFn; prevI = I3; }
        }
        __syncthreads();  // B1
        const unsigned flags = sFlags;
        const bool honest = (flags & 1u) != 0u;
        // trace t0->t1 if not already done
        if (!trDone1) {
            const float4 q = *(const float4*)&sXO[0];
            trA.x = clmp1((1.f - eA0.x) * trA.x + eA0.x * (xA0 * q.x));
            trA.y = clmp1((1.f - eA0.y) * trA.y + eA0.y * (xA0 * q.y));
            trA.z = clmp1((1.f - eA0.z) * trA.z + eA0.z * (xA0 * q.z));
            trA.w = clmp1((1.f - eA0.w) * trA.w + eA0.w * (xA0 * q.w));
            trB.x = clmp1((1.f - eB0.x) * trB.x + eB0.x * (xB0 * q.x));
            trB.y = clmp1((1.f - eB0.y) * trB.y + eB0.y * (xB0 * q.y));
            trB.z = clmp1((1.f - eB0.z) * trB.z + eB0.z * (xB0 * q.z));
            trB.w = clmp1((1.f - eB0.w) * trB.w + eB0.w * (xB0 * q.w));
        }
        if (honest) {   // gEx failed: recompute e1/xo1 honestly (rare/never)
            dotTr(xA1, xB1);
            __syncthreads();
            if (tid < 4) {
                float l = wredL[0][tid] + wredL[1][tid] + wredL[2][tid] + wredL[3][tid];
                e1 = __expf(l);
                float S1 = SP + SQ / S0;
                xo1 = e1 / S1; sXO[4 + tid] = xo1;
            }
            __syncthreads();
        }
        if (tid == 64) {
            *(float4*)&out[(size_t)sb * OUT_F + col0] = *(const float4*)&sXO[0];
            *(float4*)&out[(size_t)(sb + 1) * OUT_F + col0] = *(const float4*)&sXO[4];
        }
        if (r == NR - 1) break;
        // trace t1->t2
        {
            const float4 q = *(const float4*)&sXO[4];
            trA.x = clmp1((1.f - eA1.x) * trA.x + eA1.x * (xA1 * q.x));
            trA.y = clmp1((1.f - eA1.y) * trA.y + eA1.y * (xA1 * q.y));
            trA.z = clmp1((1.f - eA1.z) * trA.z + eA1.z * (xA1 * q.z));
            trA.w = clmp1((1.f - eA1.w) * trA.w + eA1.w * (xA1 * q.w));
            trB.x = clmp1((1.f - eB1.x) * trB.x + eB1.x * (xB1 * q.x));
            trB.y = clmp1((1.f - eB1.y) * trB.y + eB1.y * (xB1 * q.y));
            trB.z = clmp1((1.f - eB1.z) * trB.z + eB1.z * (xB1 * q.z));
            trB.w = clmp1((1.f - eB1.w) * trB.w + eB1.w * (xB1 * q.w));
        }
        if (honest) {   // honest u(t2) + P,Q from actual trace (rare/never)
            dotTr(xA2, xB2);
            __syncthreads();
            if (tid < 4) {
                float l = wredL[0][tid] + wredL[1][tid] + wredL[2][tid] + wredL[3][tid];
                e_cur = __expf(l);
                float u2 = sum4(e_cur);
                if (tid == 0)
                    __hip_atomic_store(slots + ((size_t)(r + 1) * NWG + j) * 4,
                                       __float_as_uint(u2),
                                       __ATOMIC_RELAXED, __HIP_MEMORY_SCOPE_AGENT);
            }
            // lF3 = x3·(w + a(1-eta2)tr2), I3h = x3·(a·eta2·x2)
            {
                float pL0 = xA3 * (wA.x + aA.x * (1.f - eA2.x) * trA.x) +
                            xB3 * (wB.x + aB.x * (1.f - eB2.x) * trB.x);
                float pL1 = xA3 * (wA.y + aA.y * (1.f - eA2.y) * trA.y) +
                            xB3 * (wB.y + aB.y * (1.f - eB2.y) * trB.y);
                float pL2 = xA3 * (wA.z + aA.z * (1.f - eA2.z) * trA.z) +
                            xB3 * (wB.z + aB.z * (1.f - eB2.z) * trB.z);
                float pL3 = xA3 * (wA.w + aA.w * (1.f - eA2.w) * trA.w) +
                            xB3 * (wB.w + aB.w * (1.f - eB2.w) * trB.w);
                float pI0 = xA3 * (aA.x * eA2.x * xA2) + xB3 * (aB.x * eB2.x * xB2);
                float pI1 = xA3 * (aA.y * eA2.y * xA2) + xB3 * (aB.y * eB2.y * xB2);
                float pI2 = xA3 * (aA.z * eA2.z * xA2) + xB3 * (aB.z * eB2.z * xB2);
                float pI3v = xA3 * (aA.w * eA2.w * xA2) + xB3 * (aB.w * eB2.w * xB2);
                pL0 = wsum64(pL0); pL1 = wsum64(pL1); pL2 = wsum64(pL2); pL3 = wsum64(pL3);
                pI0 = wsum64(pI0); pI1 = wsum64(pI1); pI2 = wsum64(pI2); pI3v = wsum64(pI3v);
                if ((tid & 63) == 0) {
                    wredL[wv][0] = pL0; wredL[wv][1] = pL1;
                    wredL[wv][2] = pL2; wredL[wv][3] = pL3;
                    wredL[wv][4] = pI0; wredL[wv][5] = pI1;
                    wredL[wv][6] = pI2; wredL[wv][7] = pI3v;
                }
            }
            __syncthreads();
            if (tid < 4) {
                prevLF = wredL[0][tid] + wredL[1][tid] + wredL[2][tid] + wredL[3][tid];
                prevI  = wredL[0][4 + tid] + wredL[1][4 + tid] +
                         wredL[2][4 + tid] + wredL[3][4 + tid];
                float eF = __expf(prevLF);
                float P = sum4(eF), Q = sum4(eF * prevI * e_cur);
                float xom0 = max4(sXO[tid]);      // re-derive maxes
                float xom1 = max4(sXO[4 + tid]);
                if (tid == 0) {
                    float xo2b = fminf(1.f, 32.f * fmaxf(xom0, xom1));
                    bool gH2 = (h5 + h6 * xom0 + h7 * xom1 + h8 * xo2b <= 1.f);
                    if (gH2) {
                        uint2v v2; v2.x = __float_as_uint(P); v2.y = __float_as_uint(Q);
                        unsigned* pp = slots + ((size_t)(r + 1) * NWG + j) * 4 + 2;
                        asm volatile("global_store_dwordx2 %0, %1, off sc0 sc1"
                                     :: "v"(pp), "v"(v2) : "memory");
                        sFlags = 0u;
                    } else sFlags = 2u;
                }
            }
        }
        // shadow for round r+1's publish (targets l(sb+4), l(sb+5))
        if (r <= NR - 3) doShadow();
        // ring loads + rotate (eta(sb+5),(sb+6); x(sb+6),(sb+7))
        {
            float4 nA5 = z4, nB5 = z4, nA6 = z4, nB6 = z4;
            float nx6a = 0, nx6b = 0, nx7a = 0, nx7b = 0;
            if (sb + 5 < BATCH) {
                nA5 = ld4(eb + (size_t)(sb + 5) * estep + (size_t)r0 * OUT_F);
                nB5 = ld4(eb + (size_t)(sb + 5) * estep + (size_t)r1 * OUT_F);
            }
            if (sb + 6 < BATCH) {
                nA6 = ld4(eb + (size_t)(sb + 6) * estep + (size_t)r0 * OUT_F);
                nB6 = ld4(eb + (size_t)(sb + 6) * estep + (size_t)r1 * OUT_F);
                nx6a = x[(size_t)(sb + 6) * IN_F + r0];
                nx6b = x[(size_t)(sb + 6) * IN_F + r1];
            }
            if (sb + 7 < BATCH) {
                nx7a = x[(size_t)(sb + 7) * IN_F + r0];
                nx7b = x[(size_t)(sb + 7) * IN_F + r1];
            }
            eA0 = eA2; eA1 = eA3; eA2 = eA4; eA3 = nA5; eA4 = nA6;
            eB0 = eB2; eB1 = eB3; eB2 = eB4; eB3 = nB5; eB4 = nB6;
            xA0 = xA2; xA1 = xA3; xA2 = xA4; xA3 = xA5; xA4 = nx6a; xA5 = nx7a;
            xB0 = xB2; xB1 = xB3; xB2 = xB4; xB3 = xB5; xB4 = nx6b; xB5 = nx7b;
        }
        __syncthreads();  // B2
    }
}

extern "C" void kernel_launch(void* const* d_in, const int* in_sizes, int n_in,
                              void* d_out, int out_size, void* d_ws, size_t ws_size,
                              hipStream_t stream) {
    const float* x     = (const float*)d_in[0];
    const float* eta   = (const float*)d_in[1];
    const float* w     = (const float*)d_in[2];
    // d_in[3] = b: cancels in softmax, unused
    const float* alpha = (const float*)d_in[4];
    float* out = (float*)d_out;
    unsigned int* slots = (unsigned int*)d_ws;

    // sentinel-init: 256 rounds x 128 WGs x 16B = 512 KiB
    hipMemsetAsync(d_ws, 0xFF, (size_t)NR * NWG * 16, stream);

    plastic_scan_kernel<<<dim3(NWG), dim3(TPB), 0, stream>>>(
        x, eta, w, alpha, out, slots);
}

// Round 12
// 1569.342 us; speedup vs baseline: 1.2915x; 1.0050x over previous
//
#include <hip/hip_runtime.h>
#include <stdint.h>

#define IN_F   512
#define OUT_F  512
#define BATCH  512
#define NWG    128
#define TPB    320   // wave0 = comm-only; waves 1-4 = 256 data threads
#define BAND   4

#define SENT 0xFFFFFFFFu

typedef unsigned int uint2v __attribute__((ext_vector_type(2)));

// raw barrier: flush LDS ops, do NOT drain vmem (unlike __syncthreads, which
// the compiler lowers with a full vmcnt(0) drain -- that drain put one HBM
// round-trip on every step's critical path in R2-R11)
#define BARRIER() do { \
    asm volatile("s_waitcnt lgkmcnt(0)" ::: "memory"); \
    __builtin_amdgcn_s_barrier(); \
} while (0)

static __device__ __forceinline__ float4 ld4(const float* p) {
    return *reinterpret_cast<const float4*>(p);
}
static __device__ __forceinline__ float clmp1(float v) {
    return fminf(1.0f, fmaxf(-1.0f, v));
}
static __device__ __forceinline__ float wsum(float v) {
#pragma unroll
    for (int o = 32; o > 0; o >>= 1) v += __shfl_xor(v, o);
    return v;
}
static __device__ __forceinline__ float wmaxr(float v) {
#pragma unroll
    for (int o = 32; o > 0; o >>= 1) v = fmaxf(v, __shfl_xor(v, o));
    return v;
}
static __device__ __forceinline__ float wminr(float v) {
#pragma unroll
    for (int o = 32; o > 0; o >>= 1) v = fminf(v, __shfl_xor(v, o));
    return v;
}

// msbuf[t*NWG + j] = bits of u_j(t) = sum_{c in band j} exp(l_c(t)).
// Max-free softmax fp32-safe (logits O(0.3)); sentinel never produced;
// payload rides inside the 4B word -> relaxed agent scope, no fences.
__global__ __launch_bounds__(TPB, 1) void plastic_scan_kernel(
    const float* __restrict__ x,      // [BATCH][IN_F]
    const float* __restrict__ eta,    // [BATCH][IN_F][OUT_F]
    const float* __restrict__ w,      // [IN_F][OUT_F]
    const float* __restrict__ alpha,  // [IN_F][OUT_F]
    float* __restrict__ out,          // [BATCH][OUT_F]
    unsigned int* __restrict__ msbuf) // [BATCH][NWG], sentinel 0xFF
{
    __shared__ float wred[4][12];   // [dwave][0..3]=A,[4..7]=B,[8..11]=hull
    __shared__ float wredL[4][4];   // honest-logit partials
    __shared__ float fAB[12];       // folded shadow
    __shared__ __align__(16) float sXO[4];
    __shared__ unsigned int sFlag;

    const int tid = threadIdx.x;
    const int pb  = blockIdx.x;
    const int j    = ((pb & 7) * (NWG / 8)) + (pb >> 3);  // XCD-banded remap
    const int col0 = j * BAND;
    const bool isData = (tid >= 64);
    const int dt = tid - 64;
    const int wi = (tid >> 6) - 1;
    const int r0 = dt;
    const int r1 = dt + 256;

    const size_t estep = (size_t)IN_F * OUT_F;
    const float* ebase = eta + col0;

    // ---- data-thread persistent state: 4-deep register rings ----
    float4 wA, wB, aA, aB, trA, trB;
    float4 eA[4], eB[4];              // eta ring, slot = t & 3
    float  xA[4], xB[4];              // x   ring, slot = t & 3
    if (isData) {
        wA = ld4(&w[(size_t)r0 * OUT_F + col0]);
        wB = ld4(&w[(size_t)r1 * OUT_F + col0]);
        aA = ld4(&alpha[(size_t)r0 * OUT_F + col0]);
        aB = ld4(&alpha[(size_t)r1 * OUT_F + col0]);
        trA = make_float4(0.f, 0.f, 0.f, 0.f);
        trB = make_float4(0.f, 0.f, 0.f, 0.f);
#pragma unroll
        for (int k = 0; k < 3; ++k) {
            eA[k] = ld4(ebase + (size_t)k * estep + (size_t)r0 * OUT_F);
            eB[k] = ld4(ebase + (size_t)k * estep + (size_t)r1 * OUT_F);
        }
        eA[3] = make_float4(0.f, 0.f, 0.f, 0.f);
        eB[3] = make_float4(0.f, 0.f, 0.f, 0.f);
#pragma unroll
        for (int k = 0; k < 4; ++k) {
            xA[k] = x[(size_t)k * IN_F + r0];
            xB[k] = x[(size_t)k * IN_F + r1];
        }
    }

    float e0 = 0, e1 = 0, e2 = 0, e3 = 0;   // lane0: exp(l) of current step

    // ================= prologue =================
    if (isData) {
        // honest l(0) = x(0) @ w  (trace(0)=0)
        float p0 = xA[0] * wA.x + xB[0] * wB.x;
        float p1 = xA[0] * wA.y + xB[0] * wB.y;
        float p2 = xA[0] * wA.z + xB[0] * wB.z;
        float p3 = xA[0] * wA.w + xB[0] * wB.w;
        p0 = wsum(p0); p1 = wsum(p1); p2 = wsum(p2); p3 = wsum(p3);
        if ((tid & 63) == 0) {
            wredL[wi][0] = p0; wredL[wi][1] = p1;
            wredL[wi][2] = p2; wredL[wi][3] = p3;
        }
        // shadow for publish target t=1: base=0, slope=eta(0)*x(0), dot x(1)
        float sA0 = eA[0].x * xA[0], sA1 = eA[0].y * xA[0];
        float sA2 = eA[0].z * xA[0], sA3 = eA[0].w * xA[0];
        float sB0 = eB[0].x * xB[0], sB1 = eB[0].y * xB[0];
        float sB2 = eB[0].z * xB[0], sB3 = eB[0].w * xB[0];
        float pA0 = xA[1] * wA.x + xB[1] * wB.x;
        float pA1 = xA[1] * wA.y + xB[1] * wB.y;
        float pA2 = xA[1] * wA.z + xB[1] * wB.z;
        float pA3 = xA[1] * wA.w + xB[1] * wB.w;
        float pB0 = xA[1] * (aA.x * sA0) + xB[1] * (aB.x * sB0);
        float pB1 = xA[1] * (aA.y * sA1) + xB[1] * (aB.y * sB1);
        float pB2 = xA[1] * (aA.z * sA2) + xB[1] * (aB.z * sB2);
        float pB3 = xA[1] * (aA.w * sA3) + xB[1] * (aB.w * sB3);
        float hsp = fmaxf(fmaxf(fmaxf(sA0, sA1), fmaxf(sA2, sA3)),
                          fmaxf(fmaxf(sB0, sB1), fmaxf(sB2, sB3)));
        hsp = fmaxf(hsp, 0.f);
        float hsn = fminf(fminf(fminf(sA0, sA1), fminf(sA2, sA3)),
                          fminf(fminf(sB0, sB1), fminf(sB2, sB3)));
        hsn = fminf(hsn, 0.f);
        pA0 = wsum(pA0); pA1 = wsum(pA1); pA2 = wsum(pA2); pA3 = wsum(pA3);
        pB0 = wsum(pB0); pB1 = wsum(pB1); pB2 = wsum(pB2); pB3 = wsum(pB3);
        hsp = wmaxr(hsp); hsn = wminr(hsn);
        if ((tid & 63) == 0) {
            float* wr = wred[wi];
            wr[0] = pA0; wr[1] = pA1; wr[2] = pA2; wr[3] = pA3;
            wr[4] = pB0; wr[5] = pB1; wr[6] = pB2; wr[7] = pB3;
            wr[8] = 0.f; wr[9] = hsp; wr[10] = 0.f; wr[11] = hsn;
        }
    }
    __syncthreads();
    if (tid == 0) {
        float l0 = wredL[0][0] + wredL[1][0] + wredL[2][0] + wredL[3][0];
        float l1 = wredL[0][1] + wredL[1][1] + wredL[2][1] + wredL[3][1];
        float l2 = wredL[0][2] + wredL[1][2] + wredL[2][2] + wredL[3][2];
        float l3 = wredL[0][3] + wredL[1][3] + wredL[2][3] + wredL[3][3];
        e0 = __expf(l0); e1 = __expf(l1); e2 = __expf(l2); e3 = __expf(l3);
        float u = (e0 + e1) + (e2 + e3);
        __hip_atomic_store(&msbuf[j], __float_as_uint(u),
                           __ATOMIC_RELAXED, __HIP_MEMORY_SCOPE_AGENT);
    }

    // ================= steady loop (4x unrolled; ring slots compile-time) ====
    for (int tb = 0; tb < BATCH; tb += 4) {
#pragma unroll
        for (int p = 0; p < 4; ++p) {
            const int t = tb + p;
            const int s0 = p & 3, s1 = (p + 1) & 3, s2 = (p + 2) & 3, s3 = (p + 3) & 3;

            float S = 0.f;
            float A0, A1, A2, A3, B0, B1, B2, B3, Hbp, Hsp, Hbn, Hsn;
            if (tid < 64) {
                // parallel fold (lanes 0..11), intra-wave -> no barrier needed
                if (tid < 8)
                    fAB[tid] = wred[0][tid] + wred[1][tid] + wred[2][tid] + wred[3][tid];
                else if (tid < 10)
                    fAB[tid] = fmaxf(fmaxf(wred[0][tid], wred[1][tid]),
                                     fmaxf(wred[2][tid], wred[3][tid]));
                else if (tid < 12)
                    fAB[tid] = fminf(fminf(wred[0][tid], wred[1][tid]),
                                     fminf(wred[2][tid], wred[3][tid]));
                if (tid == 0) {
                    A0 = fAB[0]; A1 = fAB[1]; A2 = fAB[2]; A3 = fAB[3];
                    B0 = fAB[4]; B1 = fAB[5]; B2 = fAB[6]; B3 = fAB[7];
                    Hbp = fAB[8]; Hsp = fAB[9]; Hbn = fAB[10]; Hsn = fAB[11];
                }
                // poll: comm wave's only outstanding vmem -> clean vmcnt(0)
                const unsigned int* pa = msbuf + (size_t)t * NWG + 2 * tid;
                uint2v v;
                for (;;) {
                    asm volatile("global_load_dwordx2 %0, %1, off sc0 sc1\n\t"
                                 "s_waitcnt vmcnt(0)"
                                 : "=v"(v) : "v"(pa) : "memory");
                    if (__all((v.x != SENT) & (v.y != SENT))) break;
                }
                S = wsum(__uint_as_float(v.x) + __uint_as_float(v.y));
            }
            if (tid == 0) {
                float rS = 1.0f / S;
                float xo0 = e0 * rS, xo1 = e1 * rS, xo2 = e2 * rS, xo3 = e3 * rS;
                unsigned int flag = 1u;
                if (t < BATCH - 1) {
                    float xom = fmaxf(fmaxf(xo0, xo1), fmaxf(xo2, xo3));
                    bool ok = (Hbp + Hsp * xom <= 1.0f) && (Hbn + Hsn * xom >= -1.0f);
                    if (ok) {
                        e0 = __expf(A0 + B0 * xo0); e1 = __expf(A1 + B1 * xo1);
                        e2 = __expf(A2 + B2 * xo2); e3 = __expf(A3 + B3 * xo3);
                        float u = (e0 + e1) + (e2 + e3);
                        __hip_atomic_store(&msbuf[(size_t)(t + 1) * NWG + j],
                                           __float_as_uint(u),
                                           __ATOMIC_RELAXED, __HIP_MEMORY_SCOPE_AGENT);
                    } else {
                        flag = 0u;  // defer: honest publish after trace update
                    }
                }
                sXO[0] = xo0; sXO[1] = xo1; sXO[2] = xo2; sXO[3] = xo3;
                sFlag = flag;
            }
            BARRIER();  // B1
            if (tid == 64) {
                *(float4*)&out[(size_t)t * OUT_F + col0] = *(const float4*)&sXO[0];
            }
            if (t == BATCH - 1) break;

            const unsigned int flag = sFlag;
            const float xo0 = sXO[0], xo1 = sXO[1], xo2 = sXO[2], xo3 = sXO[3];

            if (isData) {
                // trace(t+1) = clip((1-eta(t))*tr + eta(t)*x(t)*xo(t))
                float4 ea = eA[s0], ebv = eB[s0];
                float xpa = xA[s0], xpb = xB[s0];
                trA.x = clmp1((1.f - ea.x) * trA.x + ea.x * (xpa * xo0));
                trA.y = clmp1((1.f - ea.y) * trA.y + ea.y * (xpa * xo1));
                trA.z = clmp1((1.f - ea.z) * trA.z + ea.z * (xpa * xo2));
                trA.w = clmp1((1.f - ea.w) * trA.w + ea.w * (xpa * xo3));
                trB.x = clmp1((1.f - ebv.x) * trB.x + ebv.x * (xpb * xo0));
                trB.y = clmp1((1.f - ebv.y) * trB.y + ebv.y * (xpb * xo1));
                trB.z = clmp1((1.f - ebv.z) * trB.z + ebv.z * (xpb * xo2));
                trB.w = clmp1((1.f - ebv.w) * trB.w + ebv.w * (xpb * xo3));
            }

            if (!flag) {  // uniform, rare: honest l(t+1) from clipped trace
                if (isData) {
                    float xda = xA[s1], xdb = xB[s1];
                    float p0 = xda * (wA.x + aA.x * trA.x) + xdb * (wB.x + aB.x * trB.x);
                    float p1 = xda * (wA.y + aA.y * trA.y) + xdb * (wB.y + aB.y * trB.y);
                    float p2 = xda * (wA.z + aA.z * trA.z) + xdb * (wB.z + aB.z * trB.z);
                    float p3 = xda * (wA.w + aA.w * trA.w) + xdb * (wB.w + aB.w * trB.w);
                    p0 = wsum(p0); p1 = wsum(p1); p2 = wsum(p2); p3 = wsum(p3);
                    if ((tid & 63) == 0) {
                        wredL[wi][0] = p0; wredL[wi][1] = p1;
                        wredL[wi][2] = p2; wredL[wi][3] = p3;
                    }
                }
                BARRIER();
                if (tid == 0) {
                    float l0 = wredL[0][0] + wredL[1][0] + wredL[2][0] + wredL[3][0];
                    float l1 = wredL[0][1] + wredL[1][1] + wredL[2][1] + wredL[3][1];
                    float l2 = wredL[0][2] + wredL[1][2] + wredL[2][2] + wredL[3][2];
                    float l3 = wredL[0][3] + wredL[1][3] + wredL[2][3] + wredL[3][3];
                    e0 = __expf(l0); e1 = __expf(l1);
                    e2 = __expf(l2); e3 = __expf(l3);
                    float u = (e0 + e1) + (e2 + e3);
                    __hip_atomic_store(&msbuf[(size_t)(t + 1) * NWG + j],
                                       __float_as_uint(u),
                                       __ATOMIC_RELAXED, __HIP_MEMORY_SCOPE_AGENT);
                }
            }

            if (isData) {
                // shadow for publish target t+2: base=(1-eta(t+1))tr(t+1),
                // slope=eta(t+1)*x(t+1), dot x(t+2)
                if (t <= BATCH - 3) {
                    float4 em = eA[s1], en = eB[s1];
                    float xma = xA[s1], xmb = xB[s1];
                    float xda = xA[s2], xdb = xB[s2];
                    float bA0 = (1.f - em.x) * trA.x, bA1 = (1.f - em.y) * trA.y;
                    float bA2 = (1.f - em.z) * trA.z, bA3 = (1.f - em.w) * trA.w;
                    float bB0 = (1.f - en.x) * trB.x, bB1 = (1.f - en.y) * trB.y;
                    float bB2 = (1.f - en.z) * trB.z, bB3 = (1.f - en.w) * trB.w;
                    float sA0 = em.x * xma, sA1 = em.y * xma;
                    float sA2 = em.z * xma, sA3 = em.w * xma;
                    float sB0 = en.x * xmb, sB1 = en.y * xmb;
                    float sB2 = en.z * xmb, sB3 = en.w * xmb;
                    float pA0 = xda * (wA.x + aA.x * bA0) + xdb * (wB.x + aB.x * bB0);
                    float pA1 = xda * (wA.y + aA.y * bA1) + xdb * (wB.y + aB.y * bB1);
                    float pA2 = xda * (wA.z + aA.z * bA2) + xdb * (wB.z + aB.z * bB2);
                    float pA3 = xda * (wA.w + aA.w * bA3) + xdb * (wB.w + aB.w * bB3);
                    float pB0 = xda * (aA.x * sA0) + xdb * (aB.x * sB0);
                    float pB1 = xda * (aA.y * sA1) + xdb * (aB.y * sB1);
                    float pB2 = xda * (aA.z * sA2) + xdb * (aB.z * sB2);
                    float pB3 = xda * (aA.w * sA3) + xdb * (aB.w * sB3);
                    float hbp = fmaxf(fmaxf(fmaxf(bA0, bA1), fmaxf(bA2, bA3)),
                                      fmaxf(fmaxf(bB0, bB1), fmaxf(bB2, bB3)));
                    float hbn = fminf(fminf(fminf(bA0, bA1), fminf(bA2, bA3)),
                                      fminf(fminf(bB0, bB1), fminf(bB2, bB3)));
                    float hsp = fmaxf(fmaxf(fmaxf(sA0, sA1), fmaxf(sA2, sA3)),
                                      fmaxf(fmaxf(sB0, sB1), fmaxf(sB2, sB3)));
                    hsp = fmaxf(hsp, 0.f);
                    float hsn = fminf(fminf(fminf(sA0, sA1), fminf(sA2, sA3)),
                                      fminf(fminf(sB0, sB1), fminf(sB2, sB3)));
                    hsn = fminf(hsn, 0.f);
                    pA0 = wsum(pA0); pA1 = wsum(pA1); pA2 = wsum(pA2); pA3 = wsum(pA3);
                    pB0 = wsum(pB0); pB1 = wsum(pB1); pB2 = wsum(pB2); pB3 = wsum(pB3);
                    hbp = wmaxr(hbp); hsp = wmaxr(hsp);
                    hbn = wminr(hbn); hsn = wminr(hsn);
                    if ((tid & 63) == 0) {
                        float* wr = wred[wi];
                        wr[0] = pA0; wr[1] = pA1; wr[2] = pA2; wr[3] = pA3;
                        wr[4] = pB0; wr[5] = pB1; wr[6] = pB2; wr[7] = pB3;
                        wr[8] = hbp; wr[9] = hsp; wr[10] = hbn; wr[11] = hsn;
                    }
                }
                // issue ring refills LAST: eta(t+3)->slot s3, x(t+4)->slot s0.
                // First consumed 2 iterations from now; raw barriers keep them
                // in flight across iterations (no vmcnt(0) drain).
                if (t + 3 < BATCH) {
                    eA[s3] = ld4(ebase + (size_t)(t + 3) * estep + (size_t)r0 * OUT_F);
                    eB[s3] = ld4(ebase + (size_t)(t + 3) * estep + (size_t)r1 * OUT_F);
                }
                if (t + 4 < BATCH) {
                    xA[s0] = x[(size_t)(t + 4) * IN_F + r0];
                    xB[s0] = x[(size_t)(t + 4) * IN_F + r1];
                }
            }
            BARRIER();  // B2: wred stable for next iteration's fold
        }
    }
}

extern "C" void kernel_launch(void* const* d_in, const int* in_sizes, int n_in,
                              void* d_out, int out_size, void* d_ws, size_t ws_size,
                              hipStream_t stream) {
    const float* x     = (const float*)d_in[0];
    const float* eta   = (const float*)d_in[1];
    const float* w     = (const float*)d_in[2];
    // d_in[3] = b: scalar added to all logits -> cancels in softmax, unused
    const float* alpha = (const float*)d_in[4];
    float* out = (float*)d_out;
    unsigned int* msbuf = (unsigned int*)d_ws;

    // sentinel-init the per-step exchange slots: 512*128*4B = 256 KiB
    hipMemsetAsync(d_ws, 0xFF, (size_t)BATCH * NWG * sizeof(unsigned int), stream);

    plastic_scan_kernel<<<dim3(NWG), dim3(TPB), 0, stream>>>(
        x, eta, w, alpha, out, msbuf);
}